// Round 4
// baseline (145.730 us; speedup 1.0000x reference)
//
#include <hip/hip_runtime.h>
#include <math.h>

#define Lq 1024
#define Hq 8
#define Eq 64
#define LDW 72   // padded row length (bf16 elems); 144 B rows, 16B-aligned

// slot -> source head: _PERM=[6,2,1,7,3,0,5,4]; slots 0..6 = series {2,1,7,3,0,5,4}, slot 7 = cross head 6
#define SRC_HEAD_PACKED 0x64503712u

typedef __bf16 bf16_t;
typedef __bf16 bf16x8 __attribute__((ext_vector_type(8)));
typedef __bf16 bf16x4 __attribute__((ext_vector_type(4)));
typedef float floatx4 __attribute__((ext_vector_type(4)));

__device__ __forceinline__ bf16x8 cvt8(const float4 a, const float4 b) {
    bf16x8 r;
    r[0] = (bf16_t)a.x; r[1] = (bf16_t)a.y; r[2] = (bf16_t)a.z; r[3] = (bf16_t)a.w;
    r[4] = (bf16_t)b.x; r[5] = (bf16_t)b.y; r[6] = (bf16_t)b.z; r[7] = (bf16_t)b.w;
    return r;
}

__global__ __launch_bounds__(256, 2)
void attn_mfma(const float* __restrict__ Q, const float* __restrict__ Ks,
               const float* __restrict__ KTs, const float* __restrict__ Vs,
               const float* __restrict__ VTs, float* __restrict__ out) {
    const int p    = blockIdx.x;            // pair: tiles pA=p (small), pB=15-p (large)
    const int slot = blockIdx.y;
    const int b    = blockIdx.z;
    const int h    = (SRC_HEAD_PACKED >> (slot * 4)) & 0xF;
    const float* __restrict__ Kp = (slot == 7) ? KTs : Ks;
    const float* __restrict__ Vp = (slot == 7) ? VTs : Vs;
    const int pA = p, pB = 15 - p;

    const int tid  = threadIdx.x;
    const int wv   = tid >> 6;
    const int lane = tid & 63;
    const int ln16 = lane & 15;
    const int quad = lane >> 4;

    // double-buffered K / V^T tiles + per-q-set P buffers (55.3 KB total)
    __shared__ alignas(16) unsigned short k_lds[2][64][LDW];   // K[key][e]
    __shared__ alignas(16) unsigned short vt_lds[2][64][LDW];  // V^T[d][key]
    __shared__ alignas(16) unsigned short ptA[4][16][LDW];     // per-wave P^T (set A)
    __shared__ alignas(16) unsigned short ptB[4][16][LDW];     // per-wave P^T (set B)

    // ---- Q fragments for both q-tiles (B operand: [n=qrow][k=e]); fold scale*log2e ----
    const float qs = 0.125f * 1.44269504f;
    bf16x8 qfA[2], qfB[2];
    {
        const int rA = pA * 64 + wv * 16 + ln16;
        const int rB = pB * 64 + wv * 16 + ln16;
        const float* qa = Q + (((size_t)b * Lq + rA) * Hq + h) * Eq + quad * 8;
        const float* qb = Q + (((size_t)b * Lq + rB) * Hq + h) * Eq + quad * 8;
        #pragma unroll
        for (int ec = 0; ec < 2; ++ec) {
            float4 f0 = ((const float4*)(qa + ec * 32))[0];
            float4 f1 = ((const float4*)(qa + ec * 32))[1];
            float4 g0 = ((const float4*)(qb + ec * 32))[0];
            float4 g1 = ((const float4*)(qb + ec * 32))[1];
            f0.x*=qs; f0.y*=qs; f0.z*=qs; f0.w*=qs; f1.x*=qs; f1.y*=qs; f1.z*=qs; f1.w*=qs;
            g0.x*=qs; g0.y*=qs; g0.z*=qs; g0.w*=qs; g1.x*=qs; g1.y*=qs; g1.z*=qs; g1.w*=qs;
            qfA[ec] = cvt8(f0, f1);
            qfB[ec] = cvt8(g0, g1);
        }
    }

    floatx4 OA[4], OB[4];
    #pragma unroll
    for (int i = 0; i < 4; ++i) { OA[i] = (floatx4){0,0,0,0}; OB[i] = (floatx4){0,0,0,0}; }
    float mA = -INFINITY, lA = 0.f, mB = -INFINITY, lB = 0.f;

    // ---- staging lane assignment with bank-rotation (conflict-free writes) ----
    // K: row kj = tid>>2; e-block rotated by row -> write banks 2-way (free)
    const int kj = tid >> 2;
    const int kc = ((((tid & 3) + (tid >> 2)) & 3)) * 16;
    // V^T: dim vd = lane; key-block rotated by lane>>4 -> write banks 2-way (free)
    const int vd = lane;
    const int vk = (((tid >> 6) + (lane >> 4)) & 3) * 16;

    float4 kq[4];
    float  vq[16];
    auto load_tile = [&](int kt) {
        const float* kb = Kp + (((size_t)b * Lq + kt * 64 + kj) * Hq + h) * Eq + kc;
        kq[0] = ((const float4*)kb)[0]; kq[1] = ((const float4*)kb)[1];
        kq[2] = ((const float4*)kb)[2]; kq[3] = ((const float4*)kb)[3];
        const float* vb = Vp + (((size_t)b * Lq + kt * 64 + vk) * Hq + h) * Eq + vd;
        #pragma unroll
        for (int i = 0; i < 16; ++i) vq[i] = vb[(size_t)i * (Hq * Eq)];
    };
    auto stage = [&](int buf) {
        *(bf16x8*)&k_lds[buf][kj][kc]     = cvt8(kq[0], kq[1]);
        *(bf16x8*)&k_lds[buf][kj][kc + 8] = cvt8(kq[2], kq[3]);
        const float4* vq4 = (const float4*)vq;
        *(bf16x8*)&vt_lds[buf][vd][vk]     = cvt8(vq4[0], vq4[1]);
        *(bf16x8*)&vt_lds[buf][vd][vk + 8] = cvt8(vq4[2], vq4[3]);
    };

    auto process = [&](const bf16x8 (&qf)[2], bf16x8 (&kf)[4][2], bf16x8 (&vf)[4][2],
                       floatx4 (&O)[4], float& m, float& l, bool diag,
                       unsigned short (*ptw)[LDW]) {
        // S^T = K Q^T : C-layout col(ln16)=qrow, row(quad*4+r)=key-in-tile
        floatx4 s[4];
        #pragma unroll
        for (int nc = 0; nc < 4; ++nc) {
            floatx4 acc = (floatx4){0,0,0,0};
            acc = __builtin_amdgcn_mfma_f32_16x16x32_bf16(kf[nc][0], qf[0], acc, 0, 0, 0);
            acc = __builtin_amdgcn_mfma_f32_16x16x32_bf16(kf[nc][1], qf[1], acc, 0, 0, 0);
            s[nc] = acc;
        }
        if (diag) {
            const int rin = wv * 16 + ln16;
            #pragma unroll
            for (int nc = 0; nc < 4; ++nc)
                #pragma unroll
                for (int r = 0; r < 4; ++r)
                    if (nc * 16 + quad * 4 + r > rin) s[nc][r] = -INFINITY;
        }
        float mn = s[0][0];
        #pragma unroll
        for (int nc = 0; nc < 4; ++nc)
            #pragma unroll
            for (int r = 0; r < 4; ++r) mn = fmaxf(mn, s[nc][r]);
        mn = fmaxf(mn, __shfl_xor(mn, 16, 64));
        mn = fmaxf(mn, __shfl_xor(mn, 32, 64));
        mn = fmaxf(mn, m);
        const float alpha = __builtin_amdgcn_exp2f(m - mn);
        m = mn;
        float ps = 0.f;
        float pv[4][4];
        #pragma unroll
        for (int nc = 0; nc < 4; ++nc)
            #pragma unroll
            for (int r = 0; r < 4; ++r) { pv[nc][r] = __builtin_amdgcn_exp2f(s[nc][r] - mn); ps += pv[nc][r]; }
        ps += __shfl_xor(ps, 16, 64);
        ps += __shfl_xor(ps, 32, 64);
        l = l * alpha + ps;
        #pragma unroll
        for (int dc = 0; dc < 4; ++dc) O[dc] *= alpha;
        #pragma unroll
        for (int nc = 0; nc < 4; ++nc) {
            bf16x4 pk;
            pk[0] = (bf16_t)pv[nc][0]; pk[1] = (bf16_t)pv[nc][1];
            pk[2] = (bf16_t)pv[nc][2]; pk[3] = (bf16_t)pv[nc][3];
            *(bf16x4*)&ptw[ln16][nc * 16 + quad * 4] = pk;
        }
        bf16x8 pf0 = *(const bf16x8*)&ptw[ln16][quad * 8];
        bf16x8 pf1 = *(const bf16x8*)&ptw[ln16][32 + quad * 8];
        #pragma unroll
        for (int dc = 0; dc < 4; ++dc) {
            O[dc] = __builtin_amdgcn_mfma_f32_16x16x32_bf16(vf[dc][0], pf0, O[dc], 0, 0, 0);
            O[dc] = __builtin_amdgcn_mfma_f32_16x16x32_bf16(vf[dc][1], pf1, O[dc], 0, 0, 0);
        }
    };

    // ---- prologue: stage tile 0, prefetch tile 1 ----
    load_tile(0);
    stage(0);
    if (pB >= 1) load_tile(1);
    __syncthreads();

    for (int kt = 0; kt <= pB; ++kt) {
        const int cur = kt & 1, nxt = cur ^ 1;
        // fragment reads from current buffer (shared by both q-sets)
        bf16x8 kf[4][2], vf[4][2];
        #pragma unroll
        for (int c = 0; c < 4; ++c) {
            kf[c][0] = *(const bf16x8*)&k_lds[cur][c * 16 + ln16][quad * 8];
            kf[c][1] = *(const bf16x8*)&k_lds[cur][c * 16 + ln16][32 + quad * 8];
            vf[c][0] = *(const bf16x8*)&vt_lds[cur][c * 16 + ln16][quad * 8];
            vf[c][1] = *(const bf16x8*)&vt_lds[cur][c * 16 + ln16][32 + quad * 8];
        }
        // stage next tile (regs loaded one iter ago) + prefetch tile kt+2
        if (kt + 1 <= pB) stage(nxt);
        if (kt + 2 <= pB) load_tile(kt + 2);
        // compute (overlaps staging drain and global prefetch)
        if (kt <= pA) process(qfA, kf, vf, OA, mA, lA, kt == pA, ptA[wv]);
        process(qfB, kf, vf, OB, mB, lB, kt == pB, ptB[wv]);
        if (kt < pB) __syncthreads();
    }

    // ---- epilogue: O^T lane layout: qrow=ln16(+base), d = dc*16 + quad*4 + r ----
    {
        const float inv = 1.0f / lA;
        const int row = pA * 64 + wv * 16 + ln16;
        float* op = out + (((size_t)b * Lq + row) * Hq + slot) * Eq + quad * 4;
        #pragma unroll
        for (int dc = 0; dc < 4; ++dc) {
            float4 o; o.x = OA[dc][0] * inv; o.y = OA[dc][1] * inv;
            o.z = OA[dc][2] * inv; o.w = OA[dc][3] * inv;
            *(float4*)(op + dc * 16) = o;
        }
    }
    {
        const float inv = 1.0f / lB;
        const int row = pB * 64 + wv * 16 + ln16;
        float* op = out + (((size_t)b * Lq + row) * Hq + slot) * Eq + quad * 4;
        #pragma unroll
        for (int dc = 0; dc < 4; ++dc) {
            float4 o; o.x = OB[dc][0] * inv; o.y = OB[dc][1] * inv;
            o.z = OB[dc][2] * inv; o.w = OB[dc][3] * inv;
            *(float4*)(op + dc * 16) = o;
        }
    }
}

extern "C" void kernel_launch(void* const* d_in, const int* in_sizes, int n_in,
                              void* d_out, int out_size, void* d_ws, size_t ws_size,
                              hipStream_t stream) {
    const float* queries = (const float*)d_in[0];
    const float* keys    = (const float*)d_in[1];
    const float* keysT   = (const float*)d_in[2];
    const float* values  = (const float*)d_in[3];
    const float* valuesT = (const float*)d_in[4];
    float* out = (float*)d_out;

    dim3 grid(8, Hq, 8);   // (pair, slot, batch)
    dim3 block(256);
    attn_mfma<<<grid, block, 0, stream>>>(queries, keys, keysT, values, valuesT, out);
}